// Round 6
// baseline (691.412 us; speedup 1.0000x reference)
//
#include <hip/hip_runtime.h>

#define TSEQ 512
#define HID  64
#define NTH  512    // 8 waves: 0-3 layer0, 4-7 layer1; 16 batch/block, 256 blocks = 1/CU

typedef __attribute__((ext_vector_type(8))) short short8;
typedef __attribute__((ext_vector_type(4))) float f32x4;
typedef __attribute__((ext_vector_type(4))) unsigned int u32x4;

__device__ __forceinline__ float fsig(float x) {
    float e = __builtin_amdgcn_exp2f(x * -1.44269504088896340736f);
    return __builtin_amdgcn_rcpf(1.0f + e);
}
__device__ __forceinline__ float ftanh(float x) {
    float e = __builtin_amdgcn_exp2f(x * 2.88539008177792681472f);
    return 1.0f - 2.0f * __builtin_amdgcn_rcpf(1.0f + e);
}
__device__ __forceinline__ unsigned rne16(float f) {
    unsigned u = __builtin_bit_cast(unsigned, f);
    return ((u + 0x7fffu + ((u >> 16) & 1u)) >> 16) & 0xffffu;
}
// pack two f32 into one hi word (trunc-bf16 pair) + one lo word (rne residual pair)
__device__ __forceinline__ void packPair(float a, float b, unsigned* hw, unsigned* lw) {
    unsigned ua = __builtin_bit_cast(unsigned, a), ub = __builtin_bit_cast(unsigned, b);
    unsigned ha = ua & 0xffff0000u, hb = ub & 0xffff0000u;
    *hw = (ha >> 16) | hb;
    *lw = rne16(a - __builtin_bit_cast(float, ha)) |
          (rne16(b - __builtin_bit_cast(float, hb)) << 16);
}
// split 8 f32 weights into hi/lo bf16x8 A-fragments (element e <-> k-offset e)
__device__ __forceinline__ void packA(const float w8[8], short8* fhi, short8* flo) {
    unsigned hw[8], lw[8];
    #pragma unroll
    for (int e = 0; e < 8; ++e) {
        unsigned u  = __builtin_bit_cast(unsigned, w8[e]);
        unsigned hb = u & 0xffff0000u;
        hw[e] = u >> 16;
        lw[e] = rne16(w8[e] - __builtin_bit_cast(float, hb));
    }
    u32x4 H = { hw[0] | (hw[1] << 16), hw[2] | (hw[3] << 16),
                hw[4] | (hw[5] << 16), hw[6] | (hw[7] << 16) };
    u32x4 L = { lw[0] | (lw[1] << 16), lw[2] | (lw[3] << 16),
                lw[4] | (lw[5] << 16), lw[6] | (lw[7] << 16) };
    *fhi = __builtin_bit_cast(short8, H);
    *flo = __builtin_bit_cast(short8, L);
}

#define MFMA(a, b, c) __builtin_amdgcn_mfma_f32_16x16x32_bf16((a), (b), (c), 0, 0, 0)

// plane: [16 n-rows][32 words]; diagonal granule swizzle (granule = 4 words = 16B)
__device__ __forceinline__ short8 ld128(const unsigned* plane, int n, int q0) {
    int off = n * 32 + ((((q0 >> 2) + n) & 7) << 2);
    return __builtin_bit_cast(short8, *(const u32x4*)(plane + off));
}
__device__ __forceinline__ int w64off(int n, int q0) {
    return n * 32 + ((((q0 >> 2) + n) & 7) << 2) + (q0 & 3);
}
__device__ __forceinline__ float actstep(float ai, float af, float ag, float ao, float* c) {
    float it = fsig(ai), ft = fsig(af), gt = ftanh(ag), ot = fsig(ao);
    *c = ft * *c + it * gt;
    return ot * ftanh(*c);
}

__global__ __launch_bounds__(NTH, 2)
void lstm2_mfma(const float* __restrict__ x,
                const float* __restrict__ W_ih0, const float* __restrict__ W_hh0,
                const float* __restrict__ b_ih0, const float* __restrict__ b_hh0,
                const float* __restrict__ W_ih1, const float* __restrict__ W_hh1,
                const float* __restrict__ b_ih1, const float* __restrict__ b_hh1,
                const float* __restrict__ W_fc,  const float* __restrict__ b_fc,
                float* __restrict__ out)
{
    const int tid  = threadIdx.x;
    const int lane = tid & 63;
    const int wv   = tid >> 6;        // 0-3: layer0, 4-7: layer1
    const int rl   = lane & 15;       // MFMA row/col index = batch col n
    const int g    = lane >> 4;       // k-group 0..3
    const int b0   = blockIdx.x * 16;

    // hi/lo bf16 planes: [parity][16 n x 32 words]
    __shared__ unsigned h0hi[2][512], h0lo[2][512];
    __shared__ unsigned h1hi[2][512], h1lo[2][512];
    __shared__ unsigned xhi[2][32],  xlo[2][32];   // [parity][16 n x 2 words]
    __shared__ float fcl[64 * 17];                 // padded 16->17

    for (int i2 = tid; i2 < 1024; i2 += NTH) {
        ((unsigned*)h0hi)[i2] = 0u; ((unsigned*)h0lo)[i2] = 0u;
        ((unsigned*)h1hi)[i2] = 0u; ((unsigned*)h1lo)[i2] = 0u;
    }
    // stage x[0] into parity 0
    if (tid < 16) {
        f32x4 xv = *(const f32x4*)(x + ((size_t)(b0 + tid) * TSEQ) * 4);
        unsigned hw0, lw0, hw1, lw1;
        packPair(xv.x, xv.y, &hw0, &lw0);
        packPair(xv.z, xv.w, &hw1, &lw1);
        xhi[0][tid*2+0] = hw0; xhi[0][tid*2+1] = hw1;
        xlo[0][tid*2+0] = lw0; xlo[0][tid*2+1] = lw1;
    }
    __syncthreads();

    const f32x4 zero4 = {0.f, 0.f, 0.f, 0.f};

    if (wv < 4) {
        // ======== LAYER 0: wave w owns u in [16w,16w+16) for all 4 gates ========
        const int w = wv;
        short8 A0[4][2][2];   // [gate][s=0,1: W_hh0 k-half][hi/lo]
        short8 Ax[4];         // K-packed x-term: k0..3 Whi (x hi), k4..7 Whi (x lo), k8..11 Wlo (x hi)
        f32x4  bias4[4];
        #pragma unroll
        for (int G = 0; G < 4; ++G) {
            const int row = 64*G + 16*w + rl;
            #pragma unroll
            for (int s = 0; s < 2; ++s) {
                float w8[8];
                const float* src = W_hh0 + row*64 + s*32 + g*8;
                #pragma unroll
                for (int e = 0; e < 8; ++e) w8[e] = src[e];
                packA(w8, &A0[G][s][0], &A0[G][s][1]);
            }
            {
                unsigned h01, l01, h23, l23;
                packPair(W_ih0[row*4+0], W_ih0[row*4+1], &h01, &l01);
                packPair(W_ih0[row*4+2], W_ih0[row*4+3], &h23, &l23);
                u32x4 ax;
                if (g == 0)      ax = (u32x4){h01, h23, h01, h23};
                else if (g == 1) ax = (u32x4){l01, l23, 0u, 0u};
                else             ax = (u32x4){0u, 0u, 0u, 0u};
                Ax[G] = __builtin_bit_cast(short8, ax);
            }
            const int rb = 64*G + 16*w + 4*g;
            bias4[G].x = b_ih0[rb+0] + b_hh0[rb+0];
            bias4[G].y = b_ih0[rb+1] + b_hh0[rb+1];
            bias4[G].z = b_ih0[rb+2] + b_hh0[rb+2];
            bias4[G].w = b_ih0[rb+3] + b_hh0[rb+3];
        }
        float cst[4] = {0.f, 0.f, 0.f, 0.f};
        const int woff = w64off(rl, 8*w + 2*g);

        for (int i = 0; i <= TSEQ; ++i) {
            if (i < TSEQ) {
                const int p = i & 1;
                f32x4 xf;
                const bool doX = (w == 0) && (lane < 16) && (i + 1 < TSEQ);
                if (doX) xf = *(const f32x4*)(x + ((size_t)(b0 + lane) * TSEQ + (i+1)) * 4);

                short8 Bh0 = ld128(h0hi[p], rl, 4*g);
                short8 Bl0 = ld128(h0lo[p], rl, 4*g);
                short8 Bh1 = ld128(h0hi[p], rl, 16 + 4*g);
                short8 Bl1 = ld128(h0lo[p], rl, 16 + 4*g);
                short8 Bx;
                {
                    uint2 a = *(const uint2*)&xhi[p][rl*2];
                    uint2 b = *(const uint2*)&xlo[p][rl*2];
                    u32x4 tx;
                    if (g == 0)      tx = (u32x4){a.x, a.y, b.x, b.y};
                    else if (g == 1) tx = (u32x4){a.x, a.y, 0u, 0u};
                    else             tx = (u32x4){0u, 0u, 0u, 0u};
                    Bx = __builtin_bit_cast(short8, tx);
                }

                // 2 chains per gate (depth 4 + 3), 8 concurrent chains
                f32x4 accA[4], accB[4];
                __builtin_amdgcn_s_setprio(1);
                #pragma unroll
                for (int G = 0; G < 4; ++G) accA[G] = MFMA(A0[G][0][0], Bh0, bias4[G]);
                #pragma unroll
                for (int G = 0; G < 4; ++G) accB[G] = MFMA(A0[G][1][0], Bh1, zero4);
                #pragma unroll
                for (int G = 0; G < 4; ++G) accA[G] = MFMA(A0[G][0][0], Bl0, accA[G]);
                #pragma unroll
                for (int G = 0; G < 4; ++G) accB[G] = MFMA(A0[G][1][0], Bl1, accB[G]);
                #pragma unroll
                for (int G = 0; G < 4; ++G) accA[G] = MFMA(A0[G][0][1], Bh0, accA[G]);
                #pragma unroll
                for (int G = 0; G < 4; ++G) accB[G] = MFMA(A0[G][1][1], Bh1, accB[G]);
                #pragma unroll
                for (int G = 0; G < 4; ++G) accA[G] = MFMA(Ax[G], Bx, accA[G]);
                __builtin_amdgcn_s_setprio(0);
                f32x4 acc[4];
                #pragma unroll
                for (int G = 0; G < 4; ++G) acc[G] = accA[G] + accB[G];

                float hv[4];
                #pragma unroll
                for (int j = 0; j < 4; ++j)
                    hv[j] = actstep(acc[0][j], acc[1][j], acc[2][j], acc[3][j], &cst[j]);
                unsigned hw0, lw0, hw1, lw1;
                packPair(hv[0], hv[1], &hw0, &lw0);
                packPair(hv[2], hv[3], &hw1, &lw1);
                *(uint2*)&h0hi[p^1][woff] = make_uint2(hw0, hw1);
                *(uint2*)&h0lo[p^1][woff] = make_uint2(lw0, lw1);

                if (doX) {
                    unsigned xw0, xl0, xw1, xl1;
                    packPair(xf.x, xf.y, &xw0, &xl0);
                    packPair(xf.z, xf.w, &xw1, &xl1);
                    xhi[p^1][lane*2+0] = xw0; xhi[p^1][lane*2+1] = xw1;
                    xlo[p^1][lane*2+0] = xl0; xlo[p^1][lane*2+1] = xl1;
                }
            }
            __syncthreads();
        }
    } else {
        // ======== LAYER 1 (1-step skew): iter i computes t=i-1 ========
        const int w = wv - 4;
        short8 A1[4][4][2];   // s=0,1: W_ih1 (vs h0); s=2,3: W_hh1 (vs h1)
        f32x4  bias4[4];
        #pragma unroll
        for (int G = 0; G < 4; ++G) {
            const int row = 64*G + 16*w + rl;
            #pragma unroll
            for (int s = 0; s < 4; ++s) {
                float w8[8];
                const float* src = (s < 2) ? (W_ih1 + row*64 + s*32 + g*8)
                                           : (W_hh1 + row*64 + (s-2)*32 + g*8);
                #pragma unroll
                for (int e = 0; e < 8; ++e) w8[e] = src[e];
                packA(w8, &A1[G][s][0], &A1[G][s][1]);
            }
            const int rb = 64*G + 16*w + 4*g;
            bias4[G].x = b_ih1[rb+0] + b_hh1[rb+0];
            bias4[G].y = b_ih1[rb+1] + b_hh1[rb+1];
            bias4[G].z = b_ih1[rb+2] + b_hh1[rb+2];
            bias4[G].w = b_ih1[rb+3] + b_hh1[rb+3];
        }
        float cst[4] = {0.f, 0.f, 0.f, 0.f};
        const int woff = w64off(rl, 8*w + 2*g);
        const int u0   = 16*w + 4*g;

        for (int i = 0; i <= TSEQ; ++i) {
            if (i > 0) {
                const int p = i & 1;
                short8 Bh[4], Bl[4];
                Bh[0] = ld128(h0hi[p], rl, 4*g);      Bl[0] = ld128(h0lo[p], rl, 4*g);
                Bh[1] = ld128(h0hi[p], rl, 16 + 4*g); Bl[1] = ld128(h0lo[p], rl, 16 + 4*g);
                Bh[2] = ld128(h1hi[p], rl, 4*g);      Bl[2] = ld128(h1lo[p], rl, 4*g);
                Bh[3] = ld128(h1hi[p], rl, 16 + 4*g); Bl[3] = ld128(h1lo[p], rl, 16 + 4*g);

                // 2 chains per gate (depth 6 each), 8 concurrent chains
                f32x4 accA[4], accB[4];
                __builtin_amdgcn_s_setprio(1);
                #pragma unroll
                for (int G = 0; G < 4; ++G) accA[G] = MFMA(A1[G][0][0], Bh[0], bias4[G]);
                #pragma unroll
                for (int G = 0; G < 4; ++G) accB[G] = MFMA(A1[G][1][0], Bh[1], zero4);
                #pragma unroll
                for (int G = 0; G < 4; ++G) accA[G] = MFMA(A1[G][0][0], Bl[0], accA[G]);
                #pragma unroll
                for (int G = 0; G < 4; ++G) accB[G] = MFMA(A1[G][1][0], Bl[1], accB[G]);
                #pragma unroll
                for (int G = 0; G < 4; ++G) accA[G] = MFMA(A1[G][0][1], Bh[0], accA[G]);
                #pragma unroll
                for (int G = 0; G < 4; ++G) accB[G] = MFMA(A1[G][1][1], Bh[1], accB[G]);
                #pragma unroll
                for (int G = 0; G < 4; ++G) accA[G] = MFMA(A1[G][2][0], Bh[2], accA[G]);
                #pragma unroll
                for (int G = 0; G < 4; ++G) accB[G] = MFMA(A1[G][3][0], Bh[3], accB[G]);
                #pragma unroll
                for (int G = 0; G < 4; ++G) accA[G] = MFMA(A1[G][2][0], Bl[2], accA[G]);
                #pragma unroll
                for (int G = 0; G < 4; ++G) accB[G] = MFMA(A1[G][3][0], Bl[3], accB[G]);
                #pragma unroll
                for (int G = 0; G < 4; ++G) accA[G] = MFMA(A1[G][2][1], Bh[2], accA[G]);
                #pragma unroll
                for (int G = 0; G < 4; ++G) accB[G] = MFMA(A1[G][3][1], Bh[3], accB[G]);
                __builtin_amdgcn_s_setprio(0);
                f32x4 acc[4];
                #pragma unroll
                for (int G = 0; G < 4; ++G) acc[G] = accA[G] + accB[G];

                float hv[4];
                #pragma unroll
                for (int j = 0; j < 4; ++j)
                    hv[j] = actstep(acc[0][j], acc[1][j], acc[2][j], acc[3][j], &cst[j]);
                unsigned hw0, lw0, hw1, lw1;
                packPair(hv[0], hv[1], &hw0, &lw0);
                packPair(hv[2], hv[3], &hw1, &lw1);
                *(uint2*)&h1hi[p^1][woff] = make_uint2(hw0, hw1);
                *(uint2*)&h1lo[p^1][woff] = make_uint2(lw0, lw1);

                if (i == TSEQ) {
                    #pragma unroll
                    for (int j = 0; j < 4; ++j) fcl[(u0 + j)*17 + rl] = hv[j];
                }
            }
            __syncthreads();
        }
    }

    // ---- FC: out[b] = h1_last[b,:] . W_fc + b_fc ----
    if (tid < 16) {
        float acc = b_fc[0];
        #pragma unroll 16
        for (int u = 0; u < 64; ++u) acc += fcl[u*17 + tid] * W_fc[u];
        out[b0 + tid] = acc;
    }
}

extern "C" void kernel_launch(void* const* d_in, const int* in_sizes, int n_in,
                              void* d_out, int out_size, void* d_ws, size_t ws_size,
                              hipStream_t stream) {
    const float* x     = (const float*)d_in[0];
    const float* W_ih0 = (const float*)d_in[1];
    const float* W_hh0 = (const float*)d_in[2];
    const float* b_ih0 = (const float*)d_in[3];
    const float* b_hh0 = (const float*)d_in[4];
    const float* W_ih1 = (const float*)d_in[5];
    const float* W_hh1 = (const float*)d_in[6];
    const float* b_ih1 = (const float*)d_in[7];
    const float* b_hh1 = (const float*)d_in[8];
    const float* W_fc  = (const float*)d_in[9];
    const float* b_fc  = (const float*)d_in[10];
    float* out = (float*)d_out;

    dim3 grid(4096 / 16), block(NTH);
    hipLaunchKernelGGL(lstm2_mfma, grid, block, 0, stream,
                       x, W_ih0, W_hh0, b_ih0, b_hh0,
                       W_ih1, W_hh1, b_ih1, b_hh1, W_fc, b_fc, out);
}

// Round 7
// 605.650 us; speedup vs baseline: 1.1416x; 1.1416x over previous
//
#include <hip/hip_runtime.h>

#define TSEQ 512
#define NTH  512    // 8 waves: 0-3 layer0, 4-7 layer1; 16 batch/block, 256 blocks = 1/CU

typedef __attribute__((ext_vector_type(8))) short short8;
typedef __attribute__((ext_vector_type(4))) float f32x4;
typedef __attribute__((ext_vector_type(4))) unsigned int u32x4;

__device__ __forceinline__ unsigned rne16(float f) {
    unsigned u = __builtin_bit_cast(unsigned, f);
    return ((u + 0x7fffu + ((u >> 16) & 1u)) >> 16) & 0xffffu;
}
// pack two f32 into one hi word (trunc-bf16 pair) + one lo word (rne residual pair)
__device__ __forceinline__ void packPair(float a, float b, unsigned* hw, unsigned* lw) {
    unsigned ua = __builtin_bit_cast(unsigned, a), ub = __builtin_bit_cast(unsigned, b);
    unsigned ha = ua & 0xffff0000u, hb = ub & 0xffff0000u;
    *hw = (ha >> 16) | hb;
    *lw = rne16(a - __builtin_bit_cast(float, ha)) |
          (rne16(b - __builtin_bit_cast(float, hb)) << 16);
}
// split 8 f32 weights into hi/lo bf16x8 A-fragments (element e <-> k-offset e)
__device__ __forceinline__ void packA(const float w8[8], short8* fhi, short8* flo) {
    unsigned hw[8], lw[8];
    #pragma unroll
    for (int e = 0; e < 8; ++e) {
        unsigned u  = __builtin_bit_cast(unsigned, w8[e]);
        unsigned hb = u & 0xffff0000u;
        hw[e] = u >> 16;
        lw[e] = rne16(w8[e] - __builtin_bit_cast(float, hb));
    }
    u32x4 H = { hw[0] | (hw[1] << 16), hw[2] | (hw[3] << 16),
                hw[4] | (hw[5] << 16), hw[6] | (hw[7] << 16) };
    u32x4 L = { lw[0] | (lw[1] << 16), lw[2] | (lw[3] << 16),
                lw[4] | (lw[5] << 16), lw[6] | (lw[7] << 16) };
    *fhi = __builtin_bit_cast(short8, H);
    *flo = __builtin_bit_cast(short8, L);
}

#define MFMA(a, b, c) __builtin_amdgcn_mfma_f32_16x16x32_bf16((a), (b), (c), 0, 0, 0)

// fused LSTM unit update: 5 exp2 + 3 rcp (rcps of products instead of per-gate)
__device__ __forceinline__ float act_fused(float ai, float af, float ag, float ao, float* c) {
    const float L2E = 1.44269504088896340736f;
    float ei = __builtin_amdgcn_exp2f(-ai * L2E);          // e^{-i}
    float ef = __builtin_amdgcn_exp2f(-af * L2E);          // e^{-f}
    float eg = __builtin_amdgcn_exp2f(2.0f * L2E * ag);    // e^{2g}
    float eo = __builtin_amdgcn_exp2f(-ao * L2E);          // e^{-o}
    float sf = __builtin_amdgcn_rcpf(1.0f + ef);                       // sig(f)
    float ig = (eg - 1.0f) * __builtin_amdgcn_rcpf((1.0f + ei) * (eg + 1.0f)); // sig(i)*tanh(g)
    float cn = fmaf(*c, sf, ig);
    *c = cn;
    float ec = __builtin_amdgcn_exp2f(2.0f * L2E * cn);    // e^{2c}
    return (ec - 1.0f) * __builtin_amdgcn_rcpf((1.0f + eo) * (ec + 1.0f)); // sig(o)*tanh(c)
}

__global__ __launch_bounds__(NTH, 2)
void lstm2_mfma(const float* __restrict__ x,
                const float* __restrict__ W_ih0, const float* __restrict__ W_hh0,
                const float* __restrict__ b_ih0, const float* __restrict__ b_hh0,
                const float* __restrict__ W_ih1, const float* __restrict__ W_hh1,
                const float* __restrict__ b_ih1, const float* __restrict__ b_hh1,
                const float* __restrict__ W_fc,  const float* __restrict__ b_fc,
                float* __restrict__ out)
{
    const int tid  = threadIdx.x;
    const int lane = tid & 63;
    const int wv   = tid >> 6;        // 0-3: layer0, 4-7: layer1
    const int rl   = lane & 15;       // MFMA row/col index = batch col n
    const int g    = lane >> 4;       // k-group 0..3
    const int b0   = blockIdx.x * 16;

    // hi/lo bf16 planes, separate array per parity -> compile-time LDS bases
    __shared__ unsigned h0hiP0[512], h0hiP1[512], h0loP0[512], h0loP1[512];
    __shared__ unsigned h1hiP0[512], h1hiP1[512], h1loP0[512], h1loP1[512];
    __shared__ unsigned xhiP0[32],  xhiP1[32],  xloP0[32],  xloP1[32];
    __shared__ float fcl[64 * 17];    // padded 16->17

    for (int i2 = tid; i2 < 512; i2 += NTH) {
        h0hiP0[i2] = 0u; h0hiP1[i2] = 0u; h0loP0[i2] = 0u; h0loP1[i2] = 0u;
        h1hiP0[i2] = 0u; h1hiP1[i2] = 0u; h1loP0[i2] = 0u; h1loP1[i2] = 0u;
    }
    if (tid < 16) {   // stage x[0] into parity 0
        f32x4 xv = *(const f32x4*)(x + ((size_t)(b0 + tid) * TSEQ) * 4);
        unsigned hw0, lw0, hw1, lw1;
        packPair(xv.x, xv.y, &hw0, &lw0);
        packPair(xv.z, xv.w, &hw1, &lw1);
        xhiP0[tid*2+0] = hw0; xhiP0[tid*2+1] = hw1;
        xloP0[tid*2+0] = lw0; xloP0[tid*2+1] = lw1;
    }
    __syncthreads();

    // diagonal-swizzle offsets (precomputed once; all LDS addressing loop-invariant)
    const int offL = rl*32 + (((g + rl) & 7) << 2);         // b128 read, k-half 0 (q0=4g)
    const int offH = rl*32 + (((4 + g + rl) & 7) << 2);     // b128 read, k-half 1 (q0=16+4g)
    const int xoff = rl*2;

    if (wv < 4) {
        // ======== LAYER 0: wave w owns u in [16w,16w+16) for all 4 gates ========
        const int w = wv;
        short8 A0[4][3][2];   // [gate][s]: s=0,1 W_hh0 k-halves, s=2 W_ih0 (k0..3)
        f32x4  bias4[4];
        #pragma unroll
        for (int G = 0; G < 4; ++G) {
            const int row = 64*G + 16*w + rl;
            #pragma unroll
            for (int s = 0; s < 3; ++s) {
                float w8[8];
                if (s < 2) {
                    const float* src = W_hh0 + row*64 + s*32 + g*8;
                    #pragma unroll
                    for (int e = 0; e < 8; ++e) w8[e] = src[e];
                } else {
                    #pragma unroll
                    for (int e = 0; e < 8; ++e) w8[e] = 0.f;
                    if (g == 0) {
                        #pragma unroll
                        for (int e = 0; e < 4; ++e) w8[e] = W_ih0[row*4 + e];
                    }
                }
                packA(w8, &A0[G][s][0], &A0[G][s][1]);
            }
            const int rb = 64*G + 16*w + 4*g;
            bias4[G].x = b_ih0[rb+0] + b_hh0[rb+0];
            bias4[G].y = b_ih0[rb+1] + b_hh0[rb+1];
            bias4[G].z = b_ih0[rb+2] + b_hh0[rb+2];
            bias4[G].w = b_ih0[rb+3] + b_hh0[rb+3];
        }
        float cst[4] = {0.f, 0.f, 0.f, 0.f};
        const int q0w  = 8*w + 2*g;
        const int woff = rl*32 + ((((q0w >> 2) + rl) & 7) << 2) + (q0w & 3);
        const bool isx = (w == 0) && (lane < 16);

        auto body = [&](const unsigned* rHi, const unsigned* rLo,
                        const unsigned* rxH, const unsigned* rxL,
                        unsigned* wHi, unsigned* wLo,
                        unsigned* wxH, unsigned* wxL, int i) {
            f32x4 xf;
            const bool doX = isx && (i + 1 < TSEQ);
            if (doX) xf = *(const f32x4*)(x + ((size_t)(b0 + lane) * TSEQ + (i+1)) * 4);

            short8 Bh0 = __builtin_bit_cast(short8, *(const u32x4*)(rHi + offL));
            short8 Bl0 = __builtin_bit_cast(short8, *(const u32x4*)(rLo + offL));
            short8 Bh1 = __builtin_bit_cast(short8, *(const u32x4*)(rHi + offH));
            short8 Bl1 = __builtin_bit_cast(short8, *(const u32x4*)(rLo + offH));
            short8 Bxh, Bxl;
            {
                uint2 a = *(const uint2*)(rxH + xoff);
                uint2 b = *(const uint2*)(rxL + xoff);
                u32x4 th = { a.x, a.y, 0u, 0u };
                u32x4 tl = { b.x, b.y, 0u, 0u };
                Bxh = __builtin_bit_cast(short8, th);
                Bxl = __builtin_bit_cast(short8, tl);
            }

            f32x4 acc[4];
            __builtin_amdgcn_s_setprio(1);
            #pragma unroll
            for (int G = 0; G < 4; ++G) acc[G] = MFMA(A0[G][0][0], Bh0, bias4[G]);
            #pragma unroll
            for (int G = 0; G < 4; ++G) acc[G] = MFMA(A0[G][0][0], Bl0, acc[G]);
            #pragma unroll
            for (int G = 0; G < 4; ++G) acc[G] = MFMA(A0[G][0][1], Bh0, acc[G]);
            #pragma unroll
            for (int G = 0; G < 4; ++G) acc[G] = MFMA(A0[G][1][0], Bh1, acc[G]);
            #pragma unroll
            for (int G = 0; G < 4; ++G) acc[G] = MFMA(A0[G][1][0], Bl1, acc[G]);
            #pragma unroll
            for (int G = 0; G < 4; ++G) acc[G] = MFMA(A0[G][1][1], Bh1, acc[G]);
            #pragma unroll
            for (int G = 0; G < 4; ++G) acc[G] = MFMA(A0[G][2][0], Bxh, acc[G]);
            #pragma unroll
            for (int G = 0; G < 4; ++G) acc[G] = MFMA(A0[G][2][0], Bxl, acc[G]);
            #pragma unroll
            for (int G = 0; G < 4; ++G) acc[G] = MFMA(A0[G][2][1], Bxh, acc[G]);
            __builtin_amdgcn_s_setprio(0);

            float hv[4];
            #pragma unroll
            for (int j = 0; j < 4; ++j)
                hv[j] = act_fused(acc[0][j], acc[1][j], acc[2][j], acc[3][j], &cst[j]);
            unsigned hw0, lw0, hw1, lw1;
            packPair(hv[0], hv[1], &hw0, &lw0);
            packPair(hv[2], hv[3], &hw1, &lw1);
            *(uint2*)(wHi + woff) = make_uint2(hw0, hw1);
            *(uint2*)(wLo + woff) = make_uint2(lw0, lw1);

            if (doX) {
                unsigned xw0, xl0, xw1, xl1;
                packPair(xf.x, xf.y, &xw0, &xl0);
                packPair(xf.z, xf.w, &xw1, &xl1);
                wxH[xoff+0] = xw0; wxH[xoff+1] = xw1;
                wxL[xoff+0] = xl0; wxL[xoff+1] = xl1;
            }
        };

        body(h0hiP0,h0loP0,xhiP0,xloP0, h0hiP1,h0loP1,xhiP1,xloP1, 0); __syncthreads();
        body(h0hiP1,h0loP1,xhiP1,xloP1, h0hiP0,h0loP0,xhiP0,xloP0, 1); __syncthreads();
        for (int ii = 1; ii < 256; ++ii) {
            body(h0hiP0,h0loP0,xhiP0,xloP0, h0hiP1,h0loP1,xhiP1,xloP1, 2*ii);   __syncthreads();
            body(h0hiP1,h0loP1,xhiP1,xloP1, h0hiP0,h0loP0,xhiP0,xloP0, 2*ii+1); __syncthreads();
        }
        __syncthreads();   // i=512 slot (L1 tail)
    } else {
        // ======== LAYER 1 (1-step skew): iter i computes t=i-1 ========
        const int w = wv - 4;
        short8 A1[4][4][2];   // s=0,1: W_ih1 (vs h0); s=2,3: W_hh1 (vs h1)
        f32x4  bias4[4];
        #pragma unroll
        for (int G = 0; G < 4; ++G) {
            const int row = 64*G + 16*w + rl;
            #pragma unroll
            for (int s = 0; s < 4; ++s) {
                float w8[8];
                const float* src = (s < 2) ? (W_ih1 + row*64 + s*32 + g*8)
                                           : (W_hh1 + row*64 + (s-2)*32 + g*8);
                #pragma unroll
                for (int e = 0; e < 8; ++e) w8[e] = src[e];
                packA(w8, &A1[G][s][0], &A1[G][s][1]);
            }
            const int rb = 64*G + 16*w + 4*g;
            bias4[G].x = b_ih1[rb+0] + b_hh1[rb+0];
            bias4[G].y = b_ih1[rb+1] + b_hh1[rb+1];
            bias4[G].z = b_ih1[rb+2] + b_hh1[rb+2];
            bias4[G].w = b_ih1[rb+3] + b_hh1[rb+3];
        }
        float cst[4] = {0.f, 0.f, 0.f, 0.f};
        const int q0w  = 8*w + 2*g;
        const int woff = rl*32 + ((((q0w >> 2) + rl) & 7) << 2) + (q0w & 3);
        const int u0   = 16*w + 4*g;

        auto body = [&](const unsigned* r0H, const unsigned* r0L,
                        const unsigned* r1H, const unsigned* r1L,
                        unsigned* wHi, unsigned* wLo, bool wrFC) {
            short8 Bh[4], Bl[4];
            Bh[0] = __builtin_bit_cast(short8, *(const u32x4*)(r0H + offL));
            Bl[0] = __builtin_bit_cast(short8, *(const u32x4*)(r0L + offL));
            Bh[1] = __builtin_bit_cast(short8, *(const u32x4*)(r0H + offH));
            Bl[1] = __builtin_bit_cast(short8, *(const u32x4*)(r0L + offH));
            Bh[2] = __builtin_bit_cast(short8, *(const u32x4*)(r1H + offL));
            Bl[2] = __builtin_bit_cast(short8, *(const u32x4*)(r1L + offL));
            Bh[3] = __builtin_bit_cast(short8, *(const u32x4*)(r1H + offH));
            Bl[3] = __builtin_bit_cast(short8, *(const u32x4*)(r1L + offH));

            f32x4 acc[4];
            __builtin_amdgcn_s_setprio(1);
            #pragma unroll
            for (int G = 0; G < 4; ++G) acc[G] = MFMA(A1[G][0][0], Bh[0], bias4[G]);
            #pragma unroll
            for (int G = 0; G < 4; ++G) acc[G] = MFMA(A1[G][0][0], Bl[0], acc[G]);
            #pragma unroll
            for (int G = 0; G < 4; ++G) acc[G] = MFMA(A1[G][0][1], Bh[0], acc[G]);
            #pragma unroll
            for (int s = 1; s < 4; ++s) {
                #pragma unroll
                for (int G = 0; G < 4; ++G) acc[G] = MFMA(A1[G][s][0], Bh[s], acc[G]);
                #pragma unroll
                for (int G = 0; G < 4; ++G) acc[G] = MFMA(A1[G][s][0], Bl[s], acc[G]);
                #pragma unroll
                for (int G = 0; G < 4; ++G) acc[G] = MFMA(A1[G][s][1], Bh[s], acc[G]);
            }
            __builtin_amdgcn_s_setprio(0);

            float hv[4];
            #pragma unroll
            for (int j = 0; j < 4; ++j)
                hv[j] = act_fused(acc[0][j], acc[1][j], acc[2][j], acc[3][j], &cst[j]);
            unsigned hw0, lw0, hw1, lw1;
            packPair(hv[0], hv[1], &hw0, &lw0);
            packPair(hv[2], hv[3], &hw1, &lw1);
            *(uint2*)(wHi + woff) = make_uint2(hw0, hw1);
            *(uint2*)(wLo + woff) = make_uint2(lw0, lw1);
            if (wrFC) {
                #pragma unroll
                for (int j = 0; j < 4; ++j) fcl[(u0 + j)*17 + rl] = hv[j];
            }
        };

        __syncthreads();                                                         // i=0 (idle)
        body(h0hiP1,h0loP1,h1hiP1,h1loP1, h1hiP0,h1loP0, false); __syncthreads(); // i=1
        for (int ii = 1; ii < 256; ++ii) {
            body(h0hiP0,h0loP0,h1hiP0,h1loP0, h1hiP1,h1loP1, false); __syncthreads(); // i=2ii
            body(h0hiP1,h0loP1,h1hiP1,h1loP1, h1hiP0,h1loP0, false); __syncthreads(); // i=2ii+1
        }
        body(h0hiP0,h0loP0,h1hiP0,h1loP0, h1hiP1,h1loP1, true);  __syncthreads(); // i=512 (t=511)
    }

    // ---- FC: out[b] = h1_last[b,:] . W_fc + b_fc ----
    if (tid < 16) {
        float acc = b_fc[0];
        #pragma unroll 16
        for (int u = 0; u < 64; ++u) acc += fcl[u*17 + tid] * W_fc[u];
        out[b0 + tid] = acc;
    }
}

extern "C" void kernel_launch(void* const* d_in, const int* in_sizes, int n_in,
                              void* d_out, int out_size, void* d_ws, size_t ws_size,
                              hipStream_t stream) {
    const float* x     = (const float*)d_in[0];
    const float* W_ih0 = (const float*)d_in[1];
    const float* W_hh0 = (const float*)d_in[2];
    const float* b_ih0 = (const float*)d_in[3];
    const float* b_hh0 = (const float*)d_in[4];
    const float* W_ih1 = (const float*)d_in[5];
    const float* W_hh1 = (const float*)d_in[6];
    const float* b_ih1 = (const float*)d_in[7];
    const float* b_hh1 = (const float*)d_in[8];
    const float* W_fc  = (const float*)d_in[9];
    const float* b_fc  = (const float*)d_in[10];
    float* out = (float*)d_out;

    dim3 grid(4096 / 16), block(NTH);
    hipLaunchKernelGGL(lstm2_mfma, grid, block, 0, stream,
                       x, W_ih0, W_hh0, b_ih0, b_hh0,
                       W_ih1, W_hh1, b_ih1, b_hh1, W_fc, b_fc, out);
}

// Round 8
// 594.975 us; speedup vs baseline: 1.1621x; 1.0179x over previous
//
#include <hip/hip_runtime.h>

#define TSEQ 512
#define NTH  512    // 8 waves: 0-3 layer0, 4-7 layer1 (skew 2); 16 batch/block, 256 blocks = 1/CU

typedef __attribute__((ext_vector_type(8))) short short8;
typedef __attribute__((ext_vector_type(4))) float f32x4;
typedef __attribute__((ext_vector_type(4))) unsigned int u32x4;

__device__ __forceinline__ unsigned rne16(float f) {
    unsigned u = __builtin_bit_cast(unsigned, f);
    return ((u + 0x7fffu + ((u >> 16) & 1u)) >> 16) & 0xffffu;
}
// pack two f32 into one hi word (trunc-bf16 pair) + one lo word (rne residual pair)
__device__ __forceinline__ void packPair(float a, float b, unsigned* hw, unsigned* lw) {
    unsigned ua = __builtin_bit_cast(unsigned, a), ub = __builtin_bit_cast(unsigned, b);
    unsigned ha = ua & 0xffff0000u, hb = ub & 0xffff0000u;
    *hw = (ha >> 16) | hb;
    *lw = rne16(a - __builtin_bit_cast(float, ha)) |
          (rne16(b - __builtin_bit_cast(float, hb)) << 16);
}
// split 8 f32 weights into hi/lo bf16x8 A-fragments (element e <-> k-offset e)
__device__ __forceinline__ void packA(const float w8[8], short8* fhi, short8* flo) {
    unsigned hw[8], lw[8];
    #pragma unroll
    for (int e = 0; e < 8; ++e) {
        unsigned u  = __builtin_bit_cast(unsigned, w8[e]);
        unsigned hb = u & 0xffff0000u;
        hw[e] = u >> 16;
        lw[e] = rne16(w8[e] - __builtin_bit_cast(float, hb));
    }
    u32x4 H = { hw[0] | (hw[1] << 16), hw[2] | (hw[3] << 16),
                hw[4] | (hw[5] << 16), hw[6] | (hw[7] << 16) };
    u32x4 L = { lw[0] | (lw[1] << 16), lw[2] | (lw[3] << 16),
                lw[4] | (lw[5] << 16), lw[6] | (lw[7] << 16) };
    *fhi = __builtin_bit_cast(short8, H);
    *flo = __builtin_bit_cast(short8, L);
}

#define MFMA(a, b, c) __builtin_amdgcn_mfma_f32_16x16x32_bf16((a), (b), (c), 0, 0, 0)
#define LD128(p) __builtin_bit_cast(short8, *(const u32x4*)(p))

// fused LSTM unit update: 5 exp2 + 3 rcp
__device__ __forceinline__ float act_fused(float ai, float af, float ag, float ao, float* c) {
    const float L2E = 1.44269504088896340736f;
    float ei = __builtin_amdgcn_exp2f(-ai * L2E);
    float ef = __builtin_amdgcn_exp2f(-af * L2E);
    float eg = __builtin_amdgcn_exp2f(2.0f * L2E * ag);
    float eo = __builtin_amdgcn_exp2f(-ao * L2E);
    float sf = __builtin_amdgcn_rcpf(1.0f + ef);
    float ig = (eg - 1.0f) * __builtin_amdgcn_rcpf((1.0f + ei) * (eg + 1.0f));
    float cn = fmaf(*c, sf, ig);
    *c = cn;
    float ec = __builtin_amdgcn_exp2f(2.0f * L2E * cn);
    return (ec - 1.0f) * __builtin_amdgcn_rcpf((1.0f + eo) * (ec + 1.0f));
}

__global__ __launch_bounds__(NTH, 2)
void lstm2_mfma(const float* __restrict__ x,
                const float* __restrict__ W_ih0, const float* __restrict__ W_hh0,
                const float* __restrict__ b_ih0, const float* __restrict__ b_hh0,
                const float* __restrict__ W_ih1, const float* __restrict__ W_hh1,
                const float* __restrict__ b_ih1, const float* __restrict__ b_hh1,
                const float* __restrict__ W_fc,  const float* __restrict__ b_fc,
                float* __restrict__ out)
{
    const int tid  = threadIdx.x;
    const int lane = tid & 63;
    const int wv   = tid >> 6;        // 0-3: layer0, 4-7: layer1
    const int rl   = lane & 15;       // MFMA row/col index = batch col n
    const int g    = lane >> 4;       // k-group 0..3
    const int b0   = blockIdx.x * 16;

    // hi/lo bf16 planes, depth-2 ping-pong, compile-time bases.
    // h[t] lives at parity (t+1)&1; every body(i) reads parity i&1, writes i&1^1.
    __shared__ unsigned h0hiP0[512], h0hiP1[512], h0loP0[512], h0loP1[512];
    __shared__ unsigned h1hiP0[512], h1hiP1[512], h1loP0[512], h1loP1[512];
    __shared__ float fcl[64 * 17];    // padded 16->17

    for (int i2 = tid; i2 < 512; i2 += NTH) {
        h0hiP0[i2] = 0u; h0hiP1[i2] = 0u; h0loP0[i2] = 0u; h0loP1[i2] = 0u;
        h1hiP0[i2] = 0u; h1hiP1[i2] = 0u; h1loP0[i2] = 0u; h1loP1[i2] = 0u;
    }
    __syncthreads();

    // diagonal-swizzle b128 read offsets (loop-invariant)
    const int offL = rl*32 + (((g + rl) & 7) << 2);         // k-half 0
    const int offH = rl*32 + (((4 + g + rl) & 7) << 2);     // k-half 1
    const int q0w  = 8*((wv & 3)) + 2*g;
    const int woff = rl*32 + ((((q0w >> 2) + rl) & 7) << 2) + (q0w & 3);

    if (wv < 4) {
        // ======== LAYER 0: wave w owns u in [16w,16w+16) for all 4 gates ========
        const int w = wv;
        short8 A0[4][2][2];   // [gate][k-half of W_hh0][hi/lo]
        short8 Ax[4];         // K-packed x-term: k0-3 Whi, k4-7 Whi(dup), k8-11 Wlo
        f32x4  bias4[4];
        #pragma unroll
        for (int G = 0; G < 4; ++G) {
            const int row = 64*G + 16*w + rl;
            #pragma unroll
            for (int s = 0; s < 2; ++s) {
                float w8[8];
                const float* src = W_hh0 + row*64 + s*32 + g*8;
                #pragma unroll
                for (int e = 0; e < 8; ++e) w8[e] = src[e];
                packA(w8, &A0[G][s][0], &A0[G][s][1]);
            }
            {
                unsigned h01, l01, h23, l23;
                packPair(W_ih0[row*4+0], W_ih0[row*4+1], &h01, &l01);
                packPair(W_ih0[row*4+2], W_ih0[row*4+3], &h23, &l23);
                u32x4 ax;
                if (g == 0)      ax = (u32x4){h01, h23, h01, h23};   // k0-3: Whi, k4-7: Whi(dup)
                else if (g == 1) ax = (u32x4){l01, l23, 0u, 0u};     // k8-11: Wlo
                else             ax = (u32x4){0u, 0u, 0u, 0u};
                Ax[G] = __builtin_bit_cast(short8, ax);
            }
            const int rb = 64*G + 16*w + 4*g;
            bias4[G].x = b_ih0[rb+0] + b_hh0[rb+0];
            bias4[G].y = b_ih0[rb+1] + b_hh0[rb+1];
            bias4[G].z = b_ih0[rb+2] + b_hh0[rb+2];
            bias4[G].w = b_ih0[rb+3] + b_hh0[rb+3];
        }
        float cst[4] = {0.f, 0.f, 0.f, 0.f};

        // x[t] register-prefetched; every lane loads its batch col rl (L1/L2 broadcast)
        f32x4 xcur = *(const f32x4*)(x + ((size_t)(b0 + rl) * TSEQ) * 4);

        auto body0 = [&](const unsigned* rHi, const unsigned* rLo,
                         unsigned* wHi, unsigned* wLo, int i) {
            // issue h0 reads first
            short8 Bh0 = LD128(rHi + offL);
            short8 Bl0 = LD128(rLo + offL);
            short8 Bh1 = LD128(rHi + offH);
            short8 Bl1 = LD128(rLo + offH);
            // x B-frag built in-lane from registers (k0-3 xhi, k4-7 xlo, k8-11 xhi)
            unsigned xh01, xl01, xh23, xl23;
            packPair(xcur.x, xcur.y, &xh01, &xl01);
            packPair(xcur.z, xcur.w, &xh23, &xl23);
            u32x4 tx = { (g < 2) ? xh01 : 0u, (g < 2) ? xh23 : 0u,
                         (g == 0) ? xl01 : 0u, (g == 0) ? xl23 : 0u };
            short8 Bx = __builtin_bit_cast(short8, tx);

            f32x4 acc[4];
            __builtin_amdgcn_s_setprio(1);
            // x-group first: register-only operands, no LDS wait
            #pragma unroll
            for (int G = 0; G < 4; ++G) acc[G] = MFMA(Ax[G], Bx, bias4[G]);
            #pragma unroll
            for (int G = 0; G < 4; ++G) acc[G] = MFMA(A0[G][0][0], Bh0, acc[G]);
            #pragma unroll
            for (int G = 0; G < 4; ++G) acc[G] = MFMA(A0[G][0][0], Bl0, acc[G]);
            #pragma unroll
            for (int G = 0; G < 4; ++G) acc[G] = MFMA(A0[G][0][1], Bh0, acc[G]);
            #pragma unroll
            for (int G = 0; G < 4; ++G) acc[G] = MFMA(A0[G][1][0], Bh1, acc[G]);
            #pragma unroll
            for (int G = 0; G < 4; ++G) acc[G] = MFMA(A0[G][1][0], Bl1, acc[G]);
            #pragma unroll
            for (int G = 0; G < 4; ++G) acc[G] = MFMA(A0[G][1][1], Bh1, acc[G]);
            __builtin_amdgcn_s_setprio(0);

            float hv[4];
            #pragma unroll
            for (int j = 0; j < 4; ++j)
                hv[j] = act_fused(acc[0][j], acc[1][j], acc[2][j], acc[3][j], &cst[j]);
            unsigned hw0, lw0, hw1, lw1;
            packPair(hv[0], hv[1], &hw0, &lw0);
            packPair(hv[2], hv[3], &hw1, &lw1);
            *(uint2*)(wHi + woff) = make_uint2(hw0, hw1);
            *(uint2*)(wLo + woff) = make_uint2(lw0, lw1);

            if (i + 1 < TSEQ)
                xcur = *(const f32x4*)(x + ((size_t)(b0 + rl) * TSEQ + (i + 1)) * 4);
        };

        for (int ii = 0; ii < 256; ++ii) {
            body0(h0hiP0, h0loP0, h0hiP1, h0loP1, 2*ii);     __syncthreads();  // i=2ii   (p=0)
            body0(h0hiP1, h0loP1, h0hiP0, h0loP0, 2*ii + 1); __syncthreads();  // i=2ii+1 (p=1)
        }
        __syncthreads();   // i=512 slot (L1 tail)
        __syncthreads();   // i=513 slot (L1 tail)
    } else {
        // ======== LAYER 1 (skew 2): iter i computes t=i-2; h0 frags prefetched at i-1 ====
        const int w = wv - 4;
        short8 A1[4][4][2];   // s=0,1: W_ih1 (vs h0); s=2,3: W_hh1 (vs h1)
        f32x4  bias4[4];
        #pragma unroll
        for (int G = 0; G < 4; ++G) {
            const int row = 64*G + 16*w + rl;
            #pragma unroll
            for (int s = 0; s < 4; ++s) {
                float w8[8];
                const float* src = (s < 2) ? (W_ih1 + row*64 + s*32 + g*8)
                                           : (W_hh1 + row*64 + (s-2)*32 + g*8);
                #pragma unroll
                for (int e = 0; e < 8; ++e) w8[e] = src[e];
                packA(w8, &A1[G][s][0], &A1[G][s][1]);
            }
            const int rb = 64*G + 16*w + 4*g;
            bias4[G].x = b_ih1[rb+0] + b_hh1[rb+0];
            bias4[G].y = b_ih1[rb+1] + b_hh1[rb+1];
            bias4[G].z = b_ih1[rb+2] + b_hh1[rb+2];
            bias4[G].w = b_ih1[rb+3] + b_hh1[rb+3];
        }
        float cst[4] = {0.f, 0.f, 0.f, 0.f};
        const int u0 = 16*w + 4*g;

        short8 pBh0 = {}, pBl0 = {}, pBh1 = {}, pBl1 = {};   // prefetched h0[t] frags

        auto body1 = [&](const unsigned* r1H, const unsigned* r1L,   // h1[t-1] read planes (p)
                         unsigned* wHi, unsigned* wLo,               // h1[t] write planes (p^1)
                         const unsigned* n0H, const unsigned* n0L,   // h0 prefetch planes (p)
                         bool wrFC) {
            // h1 reads issue at top; consumed 6 MFMA-groups later (latency hidden)
            short8 Bh2 = LD128(r1H + offL);
            short8 Bl2 = LD128(r1L + offL);
            short8 Bh3 = LD128(r1H + offH);
            short8 Bl3 = LD128(r1L + offH);

            f32x4 acc[4];
            __builtin_amdgcn_s_setprio(1);
            // s=0,1 on prefetched h0 frags: start immediately after barrier
            #pragma unroll
            for (int G = 0; G < 4; ++G) acc[G] = MFMA(A1[G][0][0], pBh0, bias4[G]);
            #pragma unroll
            for (int G = 0; G < 4; ++G) acc[G] = MFMA(A1[G][0][0], pBl0, acc[G]);
            #pragma unroll
            for (int G = 0; G < 4; ++G) acc[G] = MFMA(A1[G][0][1], pBh0, acc[G]);
            #pragma unroll
            for (int G = 0; G < 4; ++G) acc[G] = MFMA(A1[G][1][0], pBh1, acc[G]);
            #pragma unroll
            for (int G = 0; G < 4; ++G) acc[G] = MFMA(A1[G][1][0], pBl1, acc[G]);
            #pragma unroll
            for (int G = 0; G < 4; ++G) acc[G] = MFMA(A1[G][1][1], pBh1, acc[G]);
            // s=2,3 on just-read h1 frags
            #pragma unroll
            for (int G = 0; G < 4; ++G) acc[G] = MFMA(A1[G][2][0], Bh2, acc[G]);
            #pragma unroll
            for (int G = 0; G < 4; ++G) acc[G] = MFMA(A1[G][2][0], Bl2, acc[G]);
            #pragma unroll
            for (int G = 0; G < 4; ++G) acc[G] = MFMA(A1[G][2][1], Bh2, acc[G]);
            #pragma unroll
            for (int G = 0; G < 4; ++G) acc[G] = MFMA(A1[G][3][0], Bh3, acc[G]);
            #pragma unroll
            for (int G = 0; G < 4; ++G) acc[G] = MFMA(A1[G][3][0], Bl3, acc[G]);
            #pragma unroll
            for (int G = 0; G < 4; ++G) acc[G] = MFMA(A1[G][3][1], Bh3, acc[G]);
            __builtin_amdgcn_s_setprio(0);

            // prefetch h0[t+1] now: latency hides under act+pack+write
            pBh0 = LD128(n0H + offL);
            pBl0 = LD128(n0L + offL);
            pBh1 = LD128(n0H + offH);
            pBl1 = LD128(n0L + offH);

            float hv[4];
            #pragma unroll
            for (int j = 0; j < 4; ++j)
                hv[j] = act_fused(acc[0][j], acc[1][j], acc[2][j], acc[3][j], &cst[j]);
            unsigned hw0, lw0, hw1, lw1;
            packPair(hv[0], hv[1], &hw0, &lw0);
            packPair(hv[2], hv[3], &hw1, &lw1);
            *(uint2*)(wHi + woff) = make_uint2(hw0, hw1);
            *(uint2*)(wLo + woff) = make_uint2(lw0, lw1);
            if (wrFC) {
                #pragma unroll
                for (int j = 0; j < 4; ++j) fcl[(u0 + j)*17 + rl] = hv[j];
            }
        };

        __syncthreads();                         // i=0 (idle)
        // i=1: prefetch-only — h0[0] lives at parity 1
        pBh0 = LD128(h0hiP1 + offL);
        pBl0 = LD128(h0loP1 + offL);
        pBh1 = LD128(h0hiP1 + offH);
        pBl1 = LD128(h0loP1 + offH);
        __syncthreads();                         // i=1
        for (int ii = 0; ii < 256; ++ii) {
            // i=2+2ii (p=0): read h1@P0, write@P1, prefetch h0@P0
            body1(h1hiP0, h1loP0, h1hiP1, h1loP1, h0hiP0, h0loP0, false);     __syncthreads();
            // i=3+2ii (p=1): read h1@P1, write@P0, prefetch h0@P1; last (i=513) writes FC
            body1(h1hiP1, h1loP1, h1hiP0, h1loP0, h0hiP1, h0loP1, ii == 255); __syncthreads();
        }
    }

    // ---- FC: out[b] = h1_last[b,:] . W_fc + b_fc ----
    if (tid < 16) {
        float acc = b_fc[0];
        #pragma unroll 16
        for (int u = 0; u < 64; ++u) acc += fcl[u*17 + tid] * W_fc[u];
        out[b0 + tid] = acc;
    }
}

extern "C" void kernel_launch(void* const* d_in, const int* in_sizes, int n_in,
                              void* d_out, int out_size, void* d_ws, size_t ws_size,
                              hipStream_t stream) {
    const float* x     = (const float*)d_in[0];
    const float* W_ih0 = (const float*)d_in[1];
    const float* W_hh0 = (const float*)d_in[2];
    const float* b_ih0 = (const float*)d_in[3];
    const float* b_hh0 = (const float*)d_in[4];
    const float* W_ih1 = (const float*)d_in[5];
    const float* W_hh1 = (const float*)d_in[6];
    const float* b_ih1 = (const float*)d_in[7];
    const float* b_hh1 = (const float*)d_in[8];
    const float* W_fc  = (const float*)d_in[9];
    const float* b_fc  = (const float*)d_in[10];
    float* out = (float*)d_out;

    dim3 grid(4096 / 16), block(NTH);
    hipLaunchKernelGGL(lstm2_mfma, grid, block, 0, stream,
                       x, W_ih0, W_hh0, b_ih0, b_hh0,
                       W_ih1, W_hh1, b_ih1, b_hh1, W_fc, b_fc, out);
}